// Round 7
// baseline (21595.135 us; speedup 1.0000x reference)
//
#include <hip/hip_runtime.h>
#include <stdint.h>

#define NN 8192
#define D 256
#define DA 64

typedef unsigned short ushort_t;

// ---- f32 block reductions (256-thread blocks, 4 waves) ----
__device__ float blockSumF(float v, float* scr) {
  __syncthreads();
#pragma unroll
  for (int o = 32; o > 0; o >>= 1) v += __shfl_down(v, o, 64);
  if ((threadIdx.x & 63) == 0) scr[threadIdx.x >> 6] = v;
  __syncthreads();
  return ((scr[0] + scr[1]) + (scr[2] + scr[3]));
}
__device__ float blockMaxF(float v, float* scr) {
  __syncthreads();
#pragma unroll
  for (int o = 32; o > 0; o >>= 1) v = fmaxf(v, __shfl_down(v, o, 64));
  if ((threadIdx.x & 63) == 0) scr[threadIdx.x >> 6] = v;
  __syncthreads();
  return fmaxf(fmaxf(scr[0], scr[1]), fmaxf(scr[2], scr[3]));
}

// ---- zero a float buffer ----
__global__ void zero_kernel(float* __restrict__ p, size_t n) {
  for (size_t i = (size_t)blockIdx.x * blockDim.x + threadIdx.x; i < n;
       i += (size_t)gridDim.x * blockDim.x)
    p[i] = 0.0f;
}

// ---- den[i] = 1 + sum_j S[i][j] ----
__global__ __launch_bounds__(256) void rowsum_kernel(const float* __restrict__ S, float* __restrict__ den) {
  __shared__ float scr[4];
  int row = blockIdx.x, tid = threadIdx.x;
  const float* sr = S + (size_t)row * NN;
  float s = 0;
  for (int c = tid * 4; c < NN; c += 1024) {
    float4 u = *(const float4*)(sr + c);
    s += (u.x + u.y) + (u.z + u.w);
  }
  float tot = blockSumF(s, scr);
  if (tid == 0) den[row] = tot + 1.0f;
}

// ---- Xf_next = (S@Xf + Xf)/den : tiled f32 GEMM, fused epilogue ----
__global__ __launch_bounds__(256) void xf_gemm(const float* __restrict__ S,
                                               const float* __restrict__ XfC,
                                               const float* __restrict__ den,
                                               float* __restrict__ XfN) {
  __shared__ float As[64][65];
  __shared__ float Bs[64][65];
  int tid = threadIdx.x;
  int tx = tid & 15, ty = tid >> 4;
  int rb = blockIdx.x * 64;
  int cb = blockIdx.y * 64;
  float acc[4][4] = {};
  for (int kt = 0; kt < NN; kt += 64) {
    for (int i = tid; i < 4096; i += 256) {
      int r = i >> 6, c = i & 63;
      As[r][c] = S[(size_t)(rb + r) * NN + kt + c];
      Bs[r][c] = XfC[(size_t)(kt + r) * D + cb + c];
    }
    __syncthreads();
#pragma unroll 8
    for (int k = 0; k < 64; k++) {
      float a0 = As[ty * 4][k], a1 = As[ty * 4 + 1][k];
      float a2 = As[ty * 4 + 2][k], a3 = As[ty * 4 + 3][k];
      float b0 = Bs[k][tx * 4], b1 = Bs[k][tx * 4 + 1];
      float b2 = Bs[k][tx * 4 + 2], b3 = Bs[k][tx * 4 + 3];
      acc[0][0] += a0 * b0; acc[0][1] += a0 * b1; acc[0][2] += a0 * b2; acc[0][3] += a0 * b3;
      acc[1][0] += a1 * b0; acc[1][1] += a1 * b1; acc[1][2] += a1 * b2; acc[1][3] += a1 * b3;
      acc[2][0] += a2 * b0; acc[2][1] += a2 * b1; acc[2][2] += a2 * b2; acc[2][3] += a2 * b3;
      acc[3][0] += a3 * b0; acc[3][1] += a3 * b1; acc[3][2] += a3 * b2; acc[3][3] += a3 * b3;
    }
    __syncthreads();
  }
#pragma unroll
  for (int i = 0; i < 4; i++) {
    int r = rb + ty * 4 + i;
    float dinv = 1.0f / den[r];
#pragma unroll
    for (int j = 0; j < 4; j++) {
      int c = cb + tx * 4 + j;
      XfN[(size_t)r * D + c] = (acc[i][j] + XfC[(size_t)r * D + c]) * dinv;
    }
  }
}

// ---- q,k f32: T1 = Xa@W1^T (materialized), q = T1@W2^T, k = Xa@W3^T ----
__global__ __launch_bounds__(64) void qk32_kernel(const float* __restrict__ Xa,
    const float* __restrict__ W1, const float* __restrict__ W2, const float* __restrict__ W3,
    float* __restrict__ qf, float* __restrict__ kf) {
  __shared__ float x[D];
  __shared__ float ts[DA];
  int row = blockIdx.x, tid = threadIdx.x;
  for (int i = tid; i < D; i += 64) x[i] = Xa[(size_t)row * D + i];
  __syncthreads();
  const float* w1r = W1 + (size_t)tid * D;
  const float* w3r = W3 + (size_t)tid * D;
  float t = 0.0f, kv = 0.0f;
  for (int d = 0; d < D; d++) {
    float xv = x[d];
    t  = fmaf(xv, w1r[d], t);
    kv = fmaf(xv, w3r[d], kv);
  }
  kf[(size_t)row * DA + tid] = kv;
  ts[tid] = t;
  __syncthreads();
  const float* w2r = W2 + (size_t)tid * DA;
  float qv = 0.0f;
  for (int a = 0; a < DA; a++) qv = fmaf(ts[a], w2r[a], qv);
  qf[(size_t)row * DA + tid] = qv;
}

// ---- L[chunk] = q @ k^T  f32 ----
__global__ __launch_bounds__(256) void logits32(const float* __restrict__ qf,
    const float* __restrict__ kf, float* __restrict__ L, int rowBase) {
  __shared__ float qs[64][65];
  __shared__ float ks[64][65];
  int tid = threadIdx.x;
  int tx = tid & 15, ty = tid >> 4;
  int colTile = blockIdx.x * 64;
  int rowTile = blockIdx.y * 64;
  for (int i = tid; i < 4096; i += 256) {
    int r = i >> 6, c = i & 63;
    qs[c][r] = qf[(size_t)(rowBase + rowTile + r) * DA + c];
    ks[c][r] = kf[(size_t)(colTile + r) * DA + c];
  }
  __syncthreads();
  float acc[4][4] = {};
  for (int c = 0; c < 64; c++) {
    float a0 = qs[c][ty * 4], a1 = qs[c][ty * 4 + 1];
    float a2 = qs[c][ty * 4 + 2], a3 = qs[c][ty * 4 + 3];
    float b0 = ks[c][tx * 4], b1 = ks[c][tx * 4 + 1];
    float b2 = ks[c][tx * 4 + 2], b3 = ks[c][tx * 4 + 3];
    acc[0][0] = fmaf(a0, b0, acc[0][0]); acc[0][1] = fmaf(a0, b1, acc[0][1]);
    acc[0][2] = fmaf(a0, b2, acc[0][2]); acc[0][3] = fmaf(a0, b3, acc[0][3]);
    acc[1][0] = fmaf(a1, b0, acc[1][0]); acc[1][1] = fmaf(a1, b1, acc[1][1]);
    acc[1][2] = fmaf(a1, b2, acc[1][2]); acc[1][3] = fmaf(a1, b3, acc[1][3]);
    acc[2][0] = fmaf(a2, b0, acc[2][0]); acc[2][1] = fmaf(a2, b1, acc[2][1]);
    acc[2][2] = fmaf(a2, b2, acc[2][2]); acc[2][3] = fmaf(a2, b3, acc[2][3]);
    acc[3][0] = fmaf(a3, b0, acc[3][0]); acc[3][1] = fmaf(a3, b1, acc[3][1]);
    acc[3][2] = fmaf(a3, b2, acc[3][2]); acc[3][3] = fmaf(a3, b3, acc[3][3]);
  }
#pragma unroll
  for (int i = 0; i < 4; i++)
#pragma unroll
    for (int j = 0; j < 4; j++)
      L[(size_t)(rowTile + ty * 4 + i) * NN + colTile + tx * 4 + j] = acc[i][j];
}

// ---- FULL-ROW top-p: no cutoff, no cap. One block per row. ----
// softmax (np pairwise Z) -> full 8192 bitonic sort (desc prob, asc idx) ->
// sequential f32 cumsum with np's (cs - p) < 0.9f -> renorm -> gather.
__global__ __launch_bounds__(256) void topp_full(const float* __restrict__ L,
    const float* __restrict__ XaOld, float* __restrict__ XaNew, int rowBase) {
  __shared__ float ps[NN];       // 32 KB: logits, then probs (sorted in place)
  __shared__ ushort_t is[NN];    // 16 KB: index permutation
  __shared__ float scr[4];
  __shared__ float zsh, asum_sh;
  __shared__ int kcs;
  int tid = threadIdx.x;
  const float* Lr = L + (size_t)blockIdx.x * NN;
  float lm = -INFINITY;
  for (int j = tid; j < NN; j += 256) { float v = Lr[j]; ps[j] = v; lm = fmaxf(lm, v); }
  float m = blockMaxF(lm, scr);   // entry barrier publishes ps
  // Z = numpy pairwise_sum of exp(l - m): 64 leaves x 128 elems (8-acc base),
  // combined by contiguous binary tree (increasing-offset shuffles).
  if (tid < 64) {
    int base = tid * 128;
    float r[8];
#pragma unroll
    for (int j = 0; j < 8; j++) r[j] = expf(ps[base + j] - m);
    for (int i = 8; i < 128; i += 8)
#pragma unroll
      for (int j = 0; j < 8; j++) r[j] += expf(ps[base + i + j] - m);
    float leaf = ((r[0] + r[1]) + (r[2] + r[3])) + ((r[4] + r[5]) + (r[6] + r[7]));
#pragma unroll
    for (int off = 1; off < 64; off <<= 1) leaf += __shfl_down(leaf, off, 64);
    if (tid == 0) zsh = leaf;
  }
  __syncthreads();
  float z = zsh;
  for (int j = tid; j < NN; j += 256) { ps[j] = expf(ps[j] - m) / z; is[j] = (ushort_t)j; }
  __syncthreads();
  // full bitonic sort: descending prob, ascending index tie-break (stable-equivalent)
  for (int size = 2; size <= NN; size <<= 1) {
    for (int stride = size >> 1; stride > 0; stride >>= 1) {
      for (int i = tid; i < NN; i += 256) {
        int j2 = i ^ stride;
        if (j2 > i) {
          float va = ps[i], vb = ps[j2];
          ushort_t ia = is[i], ib = is[j2];
          bool agtb = (va > vb) || (va == vb && ia < ib);
          bool desc = ((i & size) == 0);
          if (desc ? !agtb : agtb) { ps[i] = vb; ps[j2] = va; is[i] = ib; is[j2] = ia; }
        }
      }
      __syncthreads();
    }
  }
  // literal np: sequential f32 inclusive cumsum; keep while f32(cs - p) < 0.9f
  if (tid == 0) {
    float cs = 0.0f, as = 0.0f; int kc = 0;
    while (kc < NN) {
      float p = ps[kc];
      cs += p;
      if (cs - p < 0.9f) { as += p; kc++; } else break;
    }
    kcs = kc; asum_sh = as;
  }
  __syncthreads();
  int kc = kcs;
  float asum = fmaxf(asum_sh, 1e-12f);   // jnp.maximum(A.sum, 1e-12)
  float acc = 0.0f;
  for (int i = 0; i < kc; i++)
    acc = fmaf(ps[i] / asum, XaOld[(size_t)is[i] * D + tid], acc);
  XaNew[(size_t)(rowBase + blockIdx.x) * D + tid] = acc;
}

// ---- Z += Xf@U1^T + Xa@U2^T  (4 rows per block) ----
__global__ __launch_bounds__(256) void z_accum(const float* __restrict__ Xf, const float* __restrict__ Xa,
    const float* __restrict__ U1n, const float* __restrict__ U2n, float* __restrict__ Z) {
  __shared__ float xf[4][D];
  __shared__ float xa[4][D];
  int r0 = blockIdx.x * 4, tid = threadIdx.x;
  for (int i = tid; i < 4 * D; i += 256) {
    xf[i >> 8][i & 255] = Xf[(size_t)r0 * D + i];
    xa[i >> 8][i & 255] = Xa[(size_t)r0 * D + i];
  }
  __syncthreads();
  const float* u1r = U1n + (size_t)tid * D;
  const float* u2r = U2n + (size_t)tid * D;
  float a0 = 0, a1 = 0, a2 = 0, a3 = 0, b0 = 0, b1 = 0, b2 = 0, b3 = 0;
  for (int d = 0; d < D; d += 4) {
    float4 u1 = *(const float4*)(u1r + d);
    float4 u2 = *(const float4*)(u2r + d);
    float f1[4] = {u1.x, u1.y, u1.z, u1.w};
    float f2[4] = {u2.x, u2.y, u2.z, u2.w};
#pragma unroll
    for (int j = 0; j < 4; j++) {
      int dd = d + j;
      a0 += xf[0][dd] * f1[j]; a1 += xf[1][dd] * f1[j];
      a2 += xf[2][dd] * f1[j]; a3 += xf[3][dd] * f1[j];
      b0 += xa[0][dd] * f2[j]; b1 += xa[1][dd] * f2[j];
      b2 += xa[2][dd] * f2[j]; b3 += xa[3][dd] * f2[j];
    }
  }
  Z[(size_t)(r0 + 0) * D + tid] += a0 + b0;
  Z[(size_t)(r0 + 1) * D + tid] += a1 + b1;
  Z[(size_t)(r0 + 2) * D + tid] += a2 + b2;
  Z[(size_t)(r0 + 3) * D + tid] += a3 + b3;
}

// ---- out = LayerNorm(X + Z) * g + b ----
__global__ __launch_bounds__(256) void ln_kernel(const float* __restrict__ X, const float* __restrict__ Z,
    const float* __restrict__ g, const float* __restrict__ bb, float* __restrict__ out) {
  __shared__ float scr[4];
  int row = blockIdx.x, tid = threadIdx.x;
  float h = X[(size_t)row * D + tid] + Z[(size_t)row * D + tid];
  float mu = blockSumF(h, scr) * (1.0f / 256.0f);
  float dv = h - mu;
  float var = blockSumF(dv * dv, scr) * (1.0f / 256.0f);
  float o = dv / sqrtf(var + 1e-5f) * g[tid] + bb[tid];
  out[(size_t)row * D + tid] = o;
}

extern "C" void kernel_launch(void* const* d_in, const int* in_sizes, int n_in,
                              void* d_out, int out_size, void* d_ws, size_t ws_size,
                              hipStream_t stream) {
  const float* X  = (const float*)d_in[0];
  const float* S  = (const float*)d_in[1];
  const float* W1 = (const float*)d_in[2];
  const float* W2 = (const float*)d_in[3];
  const float* W3 = (const float*)d_in[4];
  const float* U1 = (const float*)d_in[5];
  const float* U2 = (const float*)d_in[6];
  const float* g  = (const float*)d_in[7];
  const float* b  = (const float*)d_in[8];

  char* w = (char*)d_ws;
  size_t off = 0;
  auto alloc = [&](size_t bytes) {
    void* p = w + off; off += (bytes + 255) & ~(size_t)255; return p;
  };
  float* A1  = (float*)alloc((size_t)NN * D * 4);
  float* A2  = (float*)alloc((size_t)NN * D * 4);
  float* F1  = (float*)alloc((size_t)NN * D * 4);
  float* F2  = (float*)alloc((size_t)NN * D * 4);
  float* Z   = (float*)alloc((size_t)NN * D * 4);
  float* den = (float*)alloc((size_t)NN * 4);
  float* qf  = (float*)alloc((size_t)NN * DA * 4);
  float* kf  = (float*)alloc((size_t)NN * DA * 4);
  int chunk = 512;
  while (chunk > 64 && off + (size_t)chunk * NN * 4 + 4096 > ws_size) chunk >>= 1;
  float* L32 = (float*)alloc((size_t)chunk * NN * 4);
  (void)in_sizes; (void)n_in; (void)out_size;

  zero_kernel<<<1024, 256, 0, stream>>>(Z, (size_t)NN * D);
  rowsum_kernel<<<NN, 256, 0, stream>>>(S, den);

  const float* XaC = X;  float* XaN = A1;
  const float* XfC = X;  float* XfN = F1;
  for (int n = 0; n < 2; n++) {
    xf_gemm<<<dim3(128, 4), 256, 0, stream>>>(S, XfC, den, XfN);
    qk32_kernel<<<NN, 64, 0, stream>>>(XaC, W1, W2, W3, qf, kf);
    for (int c = 0; c < NN / chunk; c++) {
      logits32<<<dim3(NN / 64, chunk / 64), 256, 0, stream>>>(qf, kf, L32, c * chunk);
      topp_full<<<chunk, 256, 0, stream>>>(L32, XaC, XaN, c * chunk);
    }
    z_accum<<<2048, 256, 0, stream>>>(XfN, XaN, U1 + (size_t)n * D * D, U2 + (size_t)n * D * D, Z);
    XaC = XaN; XaN = A2;
    XfC = XfN; XfN = F2;
  }
  ln_kernel<<<NN, 256, 0, stream>>>(X, Z, g, b, (float*)d_out);
}